// Round 2
// baseline (483.260 us; speedup 1.0000x reference)
//
#include <hip/hip_runtime.h>
#include <stdint.h>

#define RES      512
#define TEXELS   (RES * RES)          // 262144
#define NPTS     1000000
#define RANK     48
#define ODIM     32
#define PPB      64                   // points per block (geo_main)
#define VMS      52                   // vm LDS row stride (floats), pad 48->52
#define OSTR     33                   // out-staging LDS row stride: 33 -> <=2-way banks
#define TT       128                  // texels per transpose block
#define TS       25                   // LDS row stride (dwords) in transpose, coprime w/ 32
#define CELLS    32768                // 32x32x32 Morton cells

typedef unsigned int u32;
typedef float vf4 __attribute__((ext_vector_type(4)));

__device__ __forceinline__ float lobf(u32 u) { return __uint_as_float(u << 16); }
__device__ __forceinline__ float hibf(u32 u) { return __uint_as_float(u & 0xffff0000u); }

__device__ __forceinline__ float ntl(const float* p) {
    return __builtin_nontemporal_load(p);
}
__device__ __forceinline__ u32 ntlu(const u32* p) {
    return __builtin_nontemporal_load(p);
}

// RNE pack two fp32 -> bf16x2 (a low, b high)
__device__ __forceinline__ u32 pkbf(float a, float b) {
    u32 x = __float_as_uint(a), y = __float_as_uint(b);
    u32 xr = (x + 0x7fffu + ((x >> 16) & 1u)) >> 16;
    u32 yr = (y + 0x7fffu + ((y >> 16) & 1u)) & 0xffff0000u;
    return xr | yr;
}

// ---------- Morton cell id (must be identical in count & scatter) -----------
__device__ __forceinline__ u32 sprd5(u32 a) {
    a &= 31u;
    a = (a | (a << 8)) & 0x100Fu;
    a = (a | (a << 4)) & 0x10C3u;
    a = (a | (a << 2)) & 0x1249u;
    return a;
}
__device__ __forceinline__ u32 cellOf(float x, float y, float z) {
    u32 cx = (u32)fminf(fmaxf(x * 32.f, 0.f), 31.f);
    u32 cy = (u32)fminf(fmaxf(y * 32.f, 0.f), 31.f);
    u32 cz = (u32)fminf(fmaxf(z * 32.f, 0.f), 31.f);
    return sprd5(cx) | (sprd5(cy) << 1) | (sprd5(cz) << 2);
}

// ---------- Pass 1a: planes [48][512][512] f32 -> [texel][ch] bf16 ----------
template <int TEXB>
__global__ __launch_bounds__(256) void transpose_planes(
    const float* __restrict__ p0, const float* __restrict__ p1,
    const float* __restrict__ p2, char* __restrict__ ws)
{
    __shared__ u32 lds[TT * TS + 8];

    int t = threadIdx.x;
    int base = blockIdx.x * TT;                     // grid.x = TEXELS/TT = 2048
    int plane = blockIdx.y;                         // uniform
    const float* src = (plane == 0) ? p0 : ((plane == 1) ? p1 : p2);

    int t7 = t & (TT - 1);                          // texel within tile
    int half = t >> 7;                              // 0/1 -> dword group
#pragma unroll
    for (int j = 0; j < 12; ++j) {
        int d = half * 12 + j;                      // dword index 0..23 (ch 2d,2d+1)
        float a = ntl(&src[(size_t)(2 * d) * TEXELS + base + t7]);
        float b = ntl(&src[(size_t)(2 * d + 1) * TEXELS + base + t7]);
        lds[t7 * TS + d] = pkbf(a, b);
    }
    __syncthreads();

    char* outp = ws + (size_t)plane * TEXELS * TEXB + (size_t)base * TEXB;
    constexpr int NS = TT * TEXB / (16 * 256);      // uint4 stores per thread
#pragma unroll
    for (int s = 0; s < NS; ++s) {
        u32 o = (u32)(s * 256 + t) * 16u;           // byte offset in block region
        u32 texel, rem;
        if (TEXB == 128) { texel = o >> 7; rem = o & 127u; }
        else {                                      // TEXB == 96: o/96 = (o>>5)/3
            texel = ((o >> 5) * 43691u) >> 17;
            rem = o - texel * 96u;
        }
        u32 dw = texel * TS + (rem >> 2);
        uint4 q = make_uint4(lds[dw], lds[dw + 1], lds[dw + 2], lds[dw + 3]);
        *(uint4*)(outp + o) = q;                    // lane-consecutive, coalesced
    }
}

// ---------- Pass 1b: lines [48][512] f32 -> [pos][ch] bf16 ------------------
template <int TEXB>
__global__ __launch_bounds__(256) void transpose_lines(
    const float* __restrict__ lz, const float* __restrict__ ly,
    const float* __restrict__ lx, char* __restrict__ ws)
{
    int id = blockIdx.x * 256 + threadIdx.x;        // grid.x = 6
    int line = id >> 9;                             // uniform per block
    int pos = id & (RES - 1);
    const float* src = (line == 0) ? lz : ((line == 1) ? ly : lx);
    char* dst = ws + (size_t)3 * TEXELS * TEXB + (size_t)line * RES * TEXB
                   + (size_t)pos * TEXB;
#pragma unroll
    for (int k = 0; k < 6; ++k) {
        uint4 q;
        q.x = pkbf(ntl(&src[(8 * k + 0) * RES + pos]), ntl(&src[(8 * k + 1) * RES + pos]));
        q.y = pkbf(ntl(&src[(8 * k + 2) * RES + pos]), ntl(&src[(8 * k + 3) * RES + pos]));
        q.z = pkbf(ntl(&src[(8 * k + 4) * RES + pos]), ntl(&src[(8 * k + 5) * RES + pos]));
        q.w = pkbf(ntl(&src[(8 * k + 6) * RES + pos]), ntl(&src[(8 * k + 7) * RES + pos]));
        *(uint4*)(dst + 16 * k) = q;
    }
}

// ---------- Binning passes --------------------------------------------------
__global__ __launch_bounds__(256) void zero_counts(u32* __restrict__ counts) {
    counts[blockIdx.x * 256 + threadIdx.x] = 0u;    // grid = CELLS/256
}

__global__ __launch_bounds__(256) void cell_count(
    const float* __restrict__ coords, u32* __restrict__ counts)
{
    int pt = blockIdx.x * 256 + threadIdx.x;
    if (pt >= NPTS) return;
    float x = ntl(&coords[3 * pt + 0]);
    float y = ntl(&coords[3 * pt + 1]);
    float z = ntl(&coords[3 * pt + 2]);
    atomicAdd(&counts[cellOf(x, y, z)], 1u);
}

// single block, 1024 threads: exclusive prefix over CELLS=32768 counters
__global__ __launch_bounds__(1024) void cell_scan(
    const u32* __restrict__ counts, u32* __restrict__ cursors)
{
    __shared__ u32 wt[16];
    int t = threadIdx.x;
    u32 local[32];
    u32 s = 0;
#pragma unroll
    for (int i = 0; i < 32; ++i) {
        local[i] = s;                               // exclusive within thread
        s += counts[t * 32 + i];
    }
    u32 tot = s;
    int lane = t & 63, w = t >> 6;
    u32 incl = tot;
#pragma unroll
    for (int d = 1; d < 64; d <<= 1) {
        u32 v = __shfl_up(incl, d);
        if (lane >= d) incl += v;
    }
    if (lane == 63) wt[w] = incl;
    __syncthreads();
    if (t == 0) {
        u32 a = 0;
#pragma unroll
        for (int i = 0; i < 16; ++i) { u32 x = wt[i]; wt[i] = a; a += x; }
    }
    __syncthreads();
    u32 base = wt[w] + (incl - tot);
#pragma unroll
    for (int i = 0; i < 32; ++i)
        cursors[t * 32 + i] = base + local[i];
}

__global__ __launch_bounds__(256) void cell_scatter(
    const float* __restrict__ coords, u32* __restrict__ cursors,
    u32* __restrict__ perm, float* __restrict__ rc)
{
    int pt = blockIdx.x * 256 + threadIdx.x;
    if (pt >= NPTS) return;
    float x = ntl(&coords[3 * pt + 0]);
    float y = ntl(&coords[3 * pt + 1]);
    float z = ntl(&coords[3 * pt + 2]);
    u32 pos = atomicAdd(&cursors[cellOf(x, y, z)], 1u);
    perm[pos] = (u32)pt;
    rc[3 * pos + 0] = x;
    rc[3 * pos + 1] = y;
    rc[3 * pos + 2] = z;
}

// ---------- Pass 2: gather + interpolate (8 lanes/pt) + LDS + project -------
__device__ __forceinline__ void prep1(float g, int& i0, int& i1, float& w) {
    float p = fminf(fmaxf((g + 1.f) * 0.5f * 511.f, 0.f), 511.f);
    float fp = floorf(p);
    i0 = (int)fp;
    i1 = min(i0 + 1, RES - 1);
    w = p - fp;
}

// SORTED: coords = Morton-reordered copy, perm maps sorted slot -> orig point.
template <int TEXB, bool SORTED>
__global__ __launch_bounds__(512, 4) void geo_main(
    const float* __restrict__ coords, const char* __restrict__ ws,
    const u32* __restrict__ perm,
    const float* __restrict__ W, const float* __restrict__ Bb,
    float* __restrict__ out)
{
    __shared__ float vm_lds[PPB * VMS];             // 13.3 KB (reused for out staging)
    __shared__ u32 opt_lds[PPB];                    // orig point id per local point

    int tid = threadIdx.x;
    int ptL = tid >> 3;                             // 0..63
    int c = tid & 7;                                // chunk: ch 6c..6c+5

    int bid = blockIdx.x;
    if (SORTED) {
        // XCD-chunked bijective swizzle (m204): consecutive Morton blocks share an XCD
        int nwg = gridDim.x;                        // 15625
        int q = nwg >> 3, r = nwg & 7;
        int xcd = bid & 7, slot = bid >> 3;
        bid = (xcd < r ? xcd * (q + 1) : r * (q + 1) + (xcd - r) * q) + slot;
    }
    int pt = bid * PPB + ptL;                       // NPTS = 15625*64 exactly

    float gx = ntl(&coords[3 * pt + 0]) * 2.f - 1.f;
    float gy = ntl(&coords[3 * pt + 1]) * 2.f - 1.f;
    float gz = ntl(&coords[3 * pt + 2]) * 2.f - 1.f;

    if (c == 0)
        opt_lds[ptL] = SORTED ? ntlu(&perm[pt]) : (u32)pt;

    int x0, x1, y0, y1, z0, z1;
    float wx, wy, wz;
    prep1(gx, x0, x1, wx);
    prep1(gy, y0, y1, wy);
    prep1(gz, z0, z1, wz);

    const size_t PW = (size_t)TEXELS * TEXB;
    const size_t LW = (size_t)RES * TEXB;
    const char* pxy = ws;
    const char* pxz = ws + PW;
    const char* pyz = ws + 2 * PW;
    const char* lzb = ws + 3 * PW;
    const char* lyb = lzb + LW;
    const char* lxb = lyb + LW;

    u32 co = 12u * (u32)c;                          // byte offset of chunk in texel

    u32 q[12][3], le[3][3], lf[3][3];
    {
        u32 offs[12];
        offs[0] = (u32)(y0 * RES + x0) * TEXB + co;
        offs[1] = (u32)(y0 * RES + x1) * TEXB + co;
        offs[2] = (u32)(y1 * RES + x0) * TEXB + co;
        offs[3] = (u32)(y1 * RES + x1) * TEXB + co;
        offs[4] = (u32)(z0 * RES + x0) * TEXB + co;
        offs[5] = (u32)(z0 * RES + x1) * TEXB + co;
        offs[6] = (u32)(z1 * RES + x0) * TEXB + co;
        offs[7] = (u32)(z1 * RES + x1) * TEXB + co;
        offs[8]  = (u32)(z0 * RES + y0) * TEXB + co;
        offs[9]  = (u32)(z0 * RES + y1) * TEXB + co;
        offs[10] = (u32)(z1 * RES + y0) * TEXB + co;
        offs[11] = (u32)(z1 * RES + y1) * TEXB + co;
        const char* bases[3] = { pxy, pxz, pyz };
#pragma unroll
        for (int p = 0; p < 3; ++p) {
#pragma unroll
            for (int k = 0; k < 4; ++k) {
                const u32* s = (const u32*)(bases[p] + offs[4 * p + k]);
                q[4 * p + k][0] = s[0];
                q[4 * p + k][1] = s[1];
                q[4 * p + k][2] = s[2];
            }
        }
        const char* lb[3] = { lzb, lyb, lxb };
        u32 l0[3] = { (u32)z0 * TEXB + co, (u32)y0 * TEXB + co, (u32)x0 * TEXB + co };
        u32 l1[3] = { (u32)z1 * TEXB + co, (u32)y1 * TEXB + co, (u32)x1 * TEXB + co };
#pragma unroll
        for (int p = 0; p < 3; ++p) {
            const u32* s0 = (const u32*)(lb[p] + l0[p]);
            const u32* s1 = (const u32*)(lb[p] + l1[p]);
            le[p][0] = s0[0]; le[p][1] = s0[1]; le[p][2] = s0[2];
            lf[p][0] = s1[0]; lf[p][1] = s1[1]; lf[p][2] = s1[2];
        }
    }

    float pw[3][4];
    pw[0][0] = (1.f - wy) * (1.f - wx); pw[0][1] = (1.f - wy) * wx;
    pw[0][2] = wy * (1.f - wx);         pw[0][3] = wy * wx;
    pw[1][0] = (1.f - wz) * (1.f - wx); pw[1][1] = (1.f - wz) * wx;
    pw[1][2] = wz * (1.f - wx);         pw[1][3] = wz * wx;
    pw[2][0] = (1.f - wz) * (1.f - wy); pw[2][1] = (1.f - wz) * wy;
    pw[2][2] = wz * (1.f - wy);         pw[2][3] = wz * wy;
    float lw[3] = { wz, wy, wx };

    float vm[6] = { 0.f, 0.f, 0.f, 0.f, 0.f, 0.f };
#pragma unroll
    for (int p = 0; p < 3; ++p) {
        float s0 = pw[p][0], s1 = pw[p][1], s2 = pw[p][2], s3 = pw[p][3];
        float il = 1.f - lw[p], wl = lw[p];
#pragma unroll
        for (int d = 0; d < 3; ++d) {               // dword d -> ch 2d, 2d+1
            u32 a = q[4 * p + 0][d], b = q[4 * p + 1][d];
            u32 cc = q[4 * p + 2][d], dd = q[4 * p + 3][d];
            float slo = s0 * lobf(a) + s1 * lobf(b) + s2 * lobf(cc) + s3 * lobf(dd);
            float shi = s0 * hibf(a) + s1 * hibf(b) + s2 * hibf(cc) + s3 * hibf(dd);
            float llo = il * lobf(le[p][d]) + wl * lobf(lf[p][d]);
            float lhi = il * hibf(le[p][d]) + wl * hibf(lf[p][d]);
            vm[2 * d + 0] = fmaf(slo, llo, vm[2 * d + 0]);
            vm[2 * d + 1] = fmaf(shi, lhi, vm[2 * d + 1]);
        }
    }

    float* vr = vm_lds + ptL * VMS + 6 * c;
    *(float2*)(vr + 0) = make_float2(vm[0], vm[1]);
    *(float2*)(vr + 2) = make_float2(vm[2], vm[3]);
    *(float2*)(vr + 4) = make_float2(vm[4], vm[5]);

    __syncthreads();

    int wav = __builtin_amdgcn_readfirstlane(tid >> 6);   // 0..7, wave-uniform
    int lane = tid & 63;                                  // local point
    int ob = wav * 4;

    const float* vmrow = vm_lds + lane * VMS;
    float4 bb = *(const float4*)(Bb + ob);                // uniform -> s_load
    float a0 = bb.x, a1 = bb.y, a2 = bb.z, a3 = bb.w;
#pragma unroll 4
    for (int k = 0; k < 12; ++k) {
        float4 v = *(const float4*)(vmrow + 4 * k);       // ds_read_b128
        float4 w0 = *(const float4*)(W + (ob + 0) * RANK + 4 * k);  // s_loads
        float4 w1 = *(const float4*)(W + (ob + 1) * RANK + 4 * k);
        float4 w2 = *(const float4*)(W + (ob + 2) * RANK + 4 * k);
        float4 w3 = *(const float4*)(W + (ob + 3) * RANK + 4 * k);
        a0 = fmaf(v.x, w0.x, a0); a0 = fmaf(v.y, w0.y, a0);
        a0 = fmaf(v.z, w0.z, a0); a0 = fmaf(v.w, w0.w, a0);
        a1 = fmaf(v.x, w1.x, a1); a1 = fmaf(v.y, w1.y, a1);
        a1 = fmaf(v.z, w1.z, a1); a1 = fmaf(v.w, w1.w, a1);
        a2 = fmaf(v.x, w2.x, a2); a2 = fmaf(v.y, w2.y, a2);
        a2 = fmaf(v.z, w2.z, a2); a2 = fmaf(v.w, w2.w, a2);
        a3 = fmaf(v.x, w3.x, a3); a3 = fmaf(v.y, w3.y, a3);
        a3 = fmaf(v.z, w3.z, a3); a3 = fmaf(v.w, w3.w, a3);
    }

    // ---- output staging: full 128B rows per wave store; rows scattered by perm
    __syncthreads();                                  // all vm_lds reads done
    {
        vf4 r; r.x = a0; r.y = a1; r.z = a2; r.w = a3;
        *(vf4*)(vm_lds + lane * OSTR + ob) = r;       // [pt][out] staging
    }
    __syncthreads();
    {
        int p8 = lane >> 3;                           // 0..7: point within wave's group
        int c2 = lane & 7;                            // 16B chunk of the 128B row
        int gp = wav * 8 + p8;
        vf4 v = *(const vf4*)(vm_lds + gp * OSTR + 4 * c2);
        size_t orow = (size_t)opt_lds[gp];
        __builtin_nontemporal_store(v, (vf4*)(out + orow * ODIM + 4 * c2));
    }
}

// ---------- Launch ----------------------------------------------------------
template <int TEXB>
static void launch_unsorted(const float* coords, const float* pxy, const float* pxz,
                            const float* pyz, const float* lz, const float* ly,
                            const float* lx, const float* W, const float* Bb,
                            float* out, char* ws, hipStream_t stream) {
    dim3 gt(TEXELS / TT, 3);
    transpose_planes<TEXB><<<gt, 256, 0, stream>>>(pxy, pxz, pyz, ws);
    transpose_lines<TEXB><<<6, 256, 0, stream>>>(lz, ly, lx, ws);
    geo_main<TEXB, false><<<NPTS / PPB, 512, 0, stream>>>(coords, ws, nullptr, W, Bb, out);
}

extern "C" void kernel_launch(void* const* d_in, const int* in_sizes, int n_in,
                              void* d_out, int out_size, void* d_ws, size_t ws_size,
                              hipStream_t stream) {
    const float* coords = (const float*)d_in[0];
    const float* pxy = (const float*)d_in[1];
    const float* pxz = (const float*)d_in[2];
    const float* pyz = (const float*)d_in[3];
    const float* lz = (const float*)d_in[4];
    const float* ly = (const float*)d_in[5];
    const float* lx = (const float*)d_in[6];
    const float* W = (const float*)d_in[7];
    const float* Bb = (const float*)d_in[8];
    float* out = (float*)d_out;
    char* ws = (char*)d_ws;

    // sorted path layout (TEXB=96)
    size_t pool96 = (size_t)3 * TEXELS * 96 + (size_t)3 * RES * 96;   // 75,644,928
    size_t o_counts = (pool96 + 255) & ~(size_t)255;
    size_t o_cursors = o_counts + (size_t)CELLS * 4;
    size_t o_perm = o_cursors + (size_t)CELLS * 4;
    size_t o_rc = o_perm + (size_t)NPTS * 4;
    size_t need_sorted = o_rc + (size_t)NPTS * 12;                    // ~91.9 MB
    size_t need128 = (size_t)3 * TEXELS * 128 + (size_t)3 * RES * 128;
    size_t need96 = pool96;

    if (ws_size >= need_sorted) {
        u32* counts = (u32*)(ws + o_counts);
        u32* cursors = (u32*)(ws + o_cursors);
        u32* perm = (u32*)(ws + o_perm);
        float* rc = (float*)(ws + o_rc);

        dim3 gt(TEXELS / TT, 3);
        transpose_planes<96><<<gt, 256, 0, stream>>>(pxy, pxz, pyz, ws);
        transpose_lines<96><<<6, 256, 0, stream>>>(lz, ly, lx, ws);
        zero_counts<<<CELLS / 256, 256, 0, stream>>>(counts);
        cell_count<<<(NPTS + 255) / 256, 256, 0, stream>>>(coords, counts);
        cell_scan<<<1, 1024, 0, stream>>>(counts, cursors);
        cell_scatter<<<(NPTS + 255) / 256, 256, 0, stream>>>(coords, cursors, perm, rc);
        geo_main<96, true><<<NPTS / PPB, 512, 0, stream>>>(rc, ws, perm, W, Bb, out);
    } else if (ws_size >= need128) {
        launch_unsorted<128>(coords, pxy, pxz, pyz, lz, ly, lx, W, Bb, out, ws, stream);
    } else {
        launch_unsorted<96>(coords, pxy, pxz, pyz, lz, ly, lx, W, Bb, out, ws, stream);
    }
}

// Round 3
// 463.378 us; speedup vs baseline: 1.0429x; 1.0429x over previous
//
#include <hip/hip_runtime.h>
#include <stdint.h>

#define RES      512
#define TEXELS   (RES * RES)          // 262144
#define NPTS     1000000
#define RANK     48
#define ODIM     32
#define PPB      64                   // points per block (geo_main)
#define VMS      52                   // vm LDS row stride (floats), pad 48->52
#define OSTR     33                   // out-staging LDS row stride
#define TT       128                  // texels per transpose tile
#define TS       25                   // LDS row stride (dwords), coprime w/ 32
#define CELLS    32768                // 32x32x32 Morton cells
#define TPALL    6144                 // transpose tile-blocks total (2048*3)
#define TPA      2560                 // tp blocks in K1
#define TPB      512                  // tp blocks in K2
#define TPC      3072                 // tp blocks in K3  (TPA+TPB+TPC = TPALL)
#define CNTB     3907                 // ceil(NPTS/256) count/scatter blocks

typedef unsigned int u32;
typedef float vf4 __attribute__((ext_vector_type(4)));

__device__ __forceinline__ float lobf(u32 u) { return __uint_as_float(u << 16); }
__device__ __forceinline__ float hibf(u32 u) { return __uint_as_float(u & 0xffff0000u); }

__device__ __forceinline__ float ntl(const float* p) {
    return __builtin_nontemporal_load(p);
}
__device__ __forceinline__ vf4 ntl4(const float* p) {
    return __builtin_nontemporal_load((const vf4*)p);
}

// RNE pack two fp32 -> bf16x2 (a low, b high)
__device__ __forceinline__ u32 pkbf(float a, float b) {
    u32 x = __float_as_uint(a), y = __float_as_uint(b);
    u32 xr = (x + 0x7fffu + ((x >> 16) & 1u)) >> 16;
    u32 yr = (y + 0x7fffu + ((y >> 16) & 1u)) & 0xffff0000u;
    return xr | yr;
}

// ---------- Morton cell id (identical in count & scatter) -------------------
__device__ __forceinline__ u32 sprd5(u32 a) {
    a &= 31u;
    a = (a | (a << 8)) & 0x100Fu;
    a = (a | (a << 4)) & 0x10C3u;
    a = (a | (a << 2)) & 0x1249u;
    return a;
}
__device__ __forceinline__ u32 cellOf(float x, float y, float z) {
    u32 cx = (u32)fminf(fmaxf(x * 32.f, 0.f), 31.f);
    u32 cy = (u32)fminf(fmaxf(y * 32.f, 0.f), 31.f);
    u32 cz = (u32)fminf(fmaxf(z * 32.f, 0.f), 31.f);
    return sprd5(cx) | (sprd5(cy) << 1) | (sprd5(cz) << 2);
}

// ---------- role: plane transpose tile (TEXB=96), float4 reads --------------
// 16 B/lane reads (1 KB/wave-inst): thread t -> texels 4*xi..4*xi+3 (xi=t&31),
// channel-pair group dg=t>>5; j=0..2 covers packed dword d = dg+8j (ch 2d,2d+1).
__device__ __forceinline__ void tp_role(int bx, int t,
    const float* __restrict__ p0, const float* __restrict__ p1,
    const float* __restrict__ p2, char* __restrict__ ws, u32* lds)
{
    int tile = bx & 2047;
    int plane = bx >> 11;                           // 2048 tiles per plane
    const float* src = (plane == 0) ? p0 : ((plane == 1) ? p1 : p2);
    int base = tile * TT;
    int xi = t & 31, dg = t >> 5;
#pragma unroll
    for (int j = 0; j < 3; ++j) {
        int d = dg + 8 * j;                         // 0..23
        vf4 a = ntl4(src + (size_t)(2 * d) * TEXELS + base + 4 * xi);
        vf4 b = ntl4(src + (size_t)(2 * d + 1) * TEXELS + base + 4 * xi);
        lds[(4 * xi + 0) * TS + d] = pkbf(a.x, b.x);
        lds[(4 * xi + 1) * TS + d] = pkbf(a.y, b.y);
        lds[(4 * xi + 2) * TS + d] = pkbf(a.z, b.z);
        lds[(4 * xi + 3) * TS + d] = pkbf(a.w, b.w);
    }
    __syncthreads();
    char* outp = ws + (size_t)plane * TEXELS * 96 + (size_t)base * 96;
#pragma unroll
    for (int s = 0; s < 3; ++s) {                   // 128*96/(16*256) = 3 stores
        u32 o = (u32)(s * 256 + t) * 16u;
        u32 texel = ((o >> 5) * 43691u) >> 17;      // o/96
        u32 rem = o - texel * 96u;
        u32 dw = texel * TS + (rem >> 2);
        uint4 q = make_uint4(lds[dw], lds[dw + 1], lds[dw + 2], lds[dw + 3]);
        *(uint4*)(outp + o) = q;                    // lane-consecutive
    }
}

// ---------- role: line transpose (TEXB=96) ----------------------------------
__device__ __forceinline__ void lines_role(int lbx, int t,
    const float* __restrict__ lz, const float* __restrict__ ly,
    const float* __restrict__ lx, char* __restrict__ ws)
{
    int id = lbx * 256 + t;                         // 6 blocks total
    int line = id >> 9;
    int pos = id & (RES - 1);
    const float* src = (line == 0) ? lz : ((line == 1) ? ly : lx);
    char* dst = ws + (size_t)3 * TEXELS * 96 + (size_t)line * RES * 96
                   + (size_t)pos * 96;
#pragma unroll
    for (int k = 0; k < 6; ++k) {
        uint4 q;
        q.x = pkbf(ntl(&src[(8 * k + 0) * RES + pos]), ntl(&src[(8 * k + 1) * RES + pos]));
        q.y = pkbf(ntl(&src[(8 * k + 2) * RES + pos]), ntl(&src[(8 * k + 3) * RES + pos]));
        q.z = pkbf(ntl(&src[(8 * k + 4) * RES + pos]), ntl(&src[(8 * k + 5) * RES + pos]));
        q.w = pkbf(ntl(&src[(8 * k + 6) * RES + pos]), ntl(&src[(8 * k + 7) * RES + pos]));
        *(uint4*)(dst + 16 * k) = q;
    }
}

// ---------- role: histogram count -------------------------------------------
__device__ __forceinline__ void count_role(int cbx, int t,
    const float* __restrict__ coords, u32* __restrict__ counts)
{
    int pt = cbx * 256 + t;
    if (pt >= NPTS) return;
    float x = ntl(&coords[3 * pt + 0]);
    float y = ntl(&coords[3 * pt + 1]);
    float z = ntl(&coords[3 * pt + 2]);
    atomicAdd(&counts[cellOf(x, y, z)], 1u);
}

// ---------- role: exclusive scan over CELLS with 256 threads ----------------
// thread t owns cells [t*128, t*128+128); two-phase (totals, then rewrite)
__device__ __forceinline__ void scan_role(int t,
    const u32* __restrict__ counts, u32* __restrict__ cursors, u32* wt)
{
    const u32* cp = counts + t * 128;
    u32 tot = 0;
#pragma unroll 16
    for (int i = 0; i < 128; ++i) tot += cp[i];
    int lane = t & 63;
    u32 incl = tot;
#pragma unroll
    for (int d2 = 1; d2 < 64; d2 <<= 1) {
        u32 v = __shfl_up(incl, d2);
        if (lane >= d2) incl += v;
    }
    int w = t >> 6;
    if (lane == 63) wt[w] = incl;
    __syncthreads();
    u32 run = incl - tot;                           // exclusive within wave
#pragma unroll
    for (int i = 0; i < 4; ++i) run += (i < w) ? wt[i] : 0u;
    u32* op = cursors + t * 128;
#pragma unroll 16
    for (int i = 0; i < 128; ++i) { u32 c2 = cp[i]; op[i] = run; run += c2; }
}

// ---------- role: scatter into sorted rc2 = (x,y,z, bits(origPt)) -----------
__device__ __forceinline__ void scatter_role(int cbx, int t,
    const float* __restrict__ coords, u32* __restrict__ cursors,
    vf4* __restrict__ rc2)
{
    int pt = cbx * 256 + t;
    if (pt >= NPTS) return;
    float x = ntl(&coords[3 * pt + 0]);
    float y = ntl(&coords[3 * pt + 1]);
    float z = ntl(&coords[3 * pt + 2]);
    u32 pos = atomicAdd(&cursors[cellOf(x, y, z)], 1u);
    vf4 v; v.x = x; v.y = y; v.z = z; v.w = __uint_as_float((u32)pt);
    rc2[pos] = v;
}

// ---------- fat kernels ------------------------------------------------------
__global__ __launch_bounds__(256) void k1_count_tp(
    const float* __restrict__ coords, u32* __restrict__ counts,
    const float* __restrict__ p0, const float* __restrict__ p1,
    const float* __restrict__ p2, char* __restrict__ ws)
{
    __shared__ u32 lds[TT * TS + 8];
    int bx = blockIdx.x, t = threadIdx.x;
    if (bx < CNTB) count_role(bx, t, coords, counts);
    else tp_role(bx - CNTB, t, p0, p1, p2, ws, lds);
}

__global__ __launch_bounds__(256) void k2_scan_lines_tp(
    const u32* __restrict__ counts, u32* __restrict__ cursors,
    const float* __restrict__ lz, const float* __restrict__ ly,
    const float* __restrict__ lx,
    const float* __restrict__ p0, const float* __restrict__ p1,
    const float* __restrict__ p2, char* __restrict__ ws)
{
    __shared__ u32 lds[TT * TS + 8];
    int bx = blockIdx.x, t = threadIdx.x;
    if (bx == 0) scan_role(t, counts, cursors, lds);
    else if (bx <= 6) lines_role(bx - 1, t, lz, ly, lx, ws);
    else tp_role(bx - 7 + TPA, t, p0, p1, p2, ws, lds);
}

__global__ __launch_bounds__(256) void k3_scatter_tp(
    const float* __restrict__ coords, u32* __restrict__ cursors,
    vf4* __restrict__ rc2,
    const float* __restrict__ p0, const float* __restrict__ p1,
    const float* __restrict__ p2, char* __restrict__ ws)
{
    __shared__ u32 lds[TT * TS + 8];
    int bx = blockIdx.x, t = threadIdx.x;
    if (bx < CNTB) scatter_role(bx, t, coords, cursors, rc2);
    else tp_role(bx - CNTB + TPA + TPB, t, p0, p1, p2, ws, lds);
}

// ---------- fallback (unsorted) transposes ----------------------------------
template <int TEXB>
__global__ __launch_bounds__(256) void transpose_planes(
    const float* __restrict__ p0, const float* __restrict__ p1,
    const float* __restrict__ p2, char* __restrict__ ws)
{
    __shared__ u32 lds[TT * TS + 8];
    int t = threadIdx.x;
    int base = blockIdx.x * TT;
    int plane = blockIdx.y;
    const float* src = (plane == 0) ? p0 : ((plane == 1) ? p1 : p2);
    int xi = t & 31, dg = t >> 5;
#pragma unroll
    for (int j = 0; j < 3; ++j) {
        int d = dg + 8 * j;
        vf4 a = ntl4(src + (size_t)(2 * d) * TEXELS + base + 4 * xi);
        vf4 b = ntl4(src + (size_t)(2 * d + 1) * TEXELS + base + 4 * xi);
        lds[(4 * xi + 0) * TS + d] = pkbf(a.x, b.x);
        lds[(4 * xi + 1) * TS + d] = pkbf(a.y, b.y);
        lds[(4 * xi + 2) * TS + d] = pkbf(a.z, b.z);
        lds[(4 * xi + 3) * TS + d] = pkbf(a.w, b.w);
    }
    __syncthreads();
    char* outp = ws + (size_t)plane * TEXELS * TEXB + (size_t)base * TEXB;
    constexpr int NS = TT * TEXB / (16 * 256);
#pragma unroll
    for (int s = 0; s < NS; ++s) {
        u32 o = (u32)(s * 256 + t) * 16u;
        u32 texel, rem;
        if (TEXB == 128) { texel = o >> 7; rem = o & 127u; }
        else { texel = ((o >> 5) * 43691u) >> 17; rem = o - texel * 96u; }
        u32 dw = texel * TS + (rem >> 2);
        uint4 q = make_uint4(lds[dw], lds[dw + 1], lds[dw + 2], lds[dw + 3]);
        *(uint4*)(outp + o) = q;
    }
}

template <int TEXB>
__global__ __launch_bounds__(256) void transpose_lines(
    const float* __restrict__ lz, const float* __restrict__ ly,
    const float* __restrict__ lx, char* __restrict__ ws)
{
    int id = blockIdx.x * 256 + threadIdx.x;
    int line = id >> 9;
    int pos = id & (RES - 1);
    const float* src = (line == 0) ? lz : ((line == 1) ? ly : lx);
    char* dst = ws + (size_t)3 * TEXELS * TEXB + (size_t)line * RES * TEXB
                   + (size_t)pos * TEXB;
#pragma unroll
    for (int k = 0; k < 6; ++k) {
        uint4 q;
        q.x = pkbf(ntl(&src[(8 * k + 0) * RES + pos]), ntl(&src[(8 * k + 1) * RES + pos]));
        q.y = pkbf(ntl(&src[(8 * k + 2) * RES + pos]), ntl(&src[(8 * k + 3) * RES + pos]));
        q.z = pkbf(ntl(&src[(8 * k + 4) * RES + pos]), ntl(&src[(8 * k + 5) * RES + pos]));
        q.w = pkbf(ntl(&src[(8 * k + 6) * RES + pos]), ntl(&src[(8 * k + 7) * RES + pos]));
        *(uint4*)(dst + 16 * k) = q;
    }
}

// ---------- Pass 2: gather + interpolate (8 lanes/pt) + LDS + project -------
__device__ __forceinline__ void prep1(float g, int& i0, int& i1, float& w) {
    float p = fminf(fmaxf((g + 1.f) * 0.5f * 511.f, 0.f), 511.f);
    float fp = floorf(p);
    i0 = (int)fp;
    i1 = min(i0 + 1, RES - 1);
    w = p - fp;
}

// SORTED: cin = rc2 (vf4: x,y,z,bits(orig)); else cin = raw coords (float*3).
template <int TEXB, bool SORTED>
__global__ __launch_bounds__(512, 4) void geo_main(
    const void* __restrict__ cin, const char* __restrict__ ws,
    const float* __restrict__ W, const float* __restrict__ Bb,
    float* __restrict__ out)
{
    __shared__ float vm_lds[PPB * VMS];             // 13.3 KB (reused for staging)
    __shared__ u32 opt_lds[PPB];                    // orig point id per local point

    int tid = threadIdx.x;
    int ptL = tid >> 3;                             // 0..63
    int c = tid & 7;                                // chunk: ch 6c..6c+5

    int bid = blockIdx.x;
    if (SORTED) {
        // XCD-chunked bijective swizzle: consecutive Morton blocks share an XCD
        int nwg = gridDim.x;                        // 15625
        int q = nwg >> 3, r = nwg & 7;
        int xcd = bid & 7, slot = bid >> 3;
        bid = (xcd < r ? xcd * (q + 1) : r * (q + 1) + (xcd - r) * q) + slot;
    }
    int pt = bid * PPB + ptL;                       // NPTS = 15625*64 exactly

    float gx, gy, gz;
    if (SORTED) {
        vf4 cc = __builtin_nontemporal_load((const vf4*)cin + pt);
        gx = cc.x * 2.f - 1.f;
        gy = cc.y * 2.f - 1.f;
        gz = cc.z * 2.f - 1.f;
        if (c == 0) opt_lds[ptL] = __float_as_uint(cc.w);
    } else {
        const float* coords = (const float*)cin;
        gx = ntl(&coords[3 * pt + 0]) * 2.f - 1.f;
        gy = ntl(&coords[3 * pt + 1]) * 2.f - 1.f;
        gz = ntl(&coords[3 * pt + 2]) * 2.f - 1.f;
        if (c == 0) opt_lds[ptL] = (u32)pt;
    }

    int x0, x1, y0, y1, z0, z1;
    float wx, wy, wz;
    prep1(gx, x0, x1, wx);
    prep1(gy, y0, y1, wy);
    prep1(gz, z0, z1, wz);

    const size_t PW = (size_t)TEXELS * TEXB;
    const size_t LW = (size_t)RES * TEXB;
    const char* pxy = ws;
    const char* pxz = ws + PW;
    const char* pyz = ws + 2 * PW;
    const char* lzb = ws + 3 * PW;
    const char* lyb = lzb + LW;
    const char* lxb = lyb + LW;

    u32 co = 12u * (u32)c;                          // byte offset of chunk in texel

    u32 q[12][3], le[3][3], lf[3][3];
    {
        u32 offs[12];
        offs[0] = (u32)(y0 * RES + x0) * TEXB + co;
        offs[1] = (u32)(y0 * RES + x1) * TEXB + co;
        offs[2] = (u32)(y1 * RES + x0) * TEXB + co;
        offs[3] = (u32)(y1 * RES + x1) * TEXB + co;
        offs[4] = (u32)(z0 * RES + x0) * TEXB + co;
        offs[5] = (u32)(z0 * RES + x1) * TEXB + co;
        offs[6] = (u32)(z1 * RES + x0) * TEXB + co;
        offs[7] = (u32)(z1 * RES + x1) * TEXB + co;
        offs[8]  = (u32)(z0 * RES + y0) * TEXB + co;
        offs[9]  = (u32)(z0 * RES + y1) * TEXB + co;
        offs[10] = (u32)(z1 * RES + y0) * TEXB + co;
        offs[11] = (u32)(z1 * RES + y1) * TEXB + co;
        const char* bases[3] = { pxy, pxz, pyz };
#pragma unroll
        for (int p = 0; p < 3; ++p) {
#pragma unroll
            for (int k = 0; k < 4; ++k) {
                const u32* s = (const u32*)(bases[p] + offs[4 * p + k]);
                q[4 * p + k][0] = s[0];
                q[4 * p + k][1] = s[1];
                q[4 * p + k][2] = s[2];
            }
        }
        const char* lb[3] = { lzb, lyb, lxb };
        u32 l0[3] = { (u32)z0 * TEXB + co, (u32)y0 * TEXB + co, (u32)x0 * TEXB + co };
        u32 l1[3] = { (u32)z1 * TEXB + co, (u32)y1 * TEXB + co, (u32)x1 * TEXB + co };
#pragma unroll
        for (int p = 0; p < 3; ++p) {
            const u32* s0 = (const u32*)(lb[p] + l0[p]);
            const u32* s1 = (const u32*)(lb[p] + l1[p]);
            le[p][0] = s0[0]; le[p][1] = s0[1]; le[p][2] = s0[2];
            lf[p][0] = s1[0]; lf[p][1] = s1[1]; lf[p][2] = s1[2];
        }
    }

    float pw[3][4];
    pw[0][0] = (1.f - wy) * (1.f - wx); pw[0][1] = (1.f - wy) * wx;
    pw[0][2] = wy * (1.f - wx);         pw[0][3] = wy * wx;
    pw[1][0] = (1.f - wz) * (1.f - wx); pw[1][1] = (1.f - wz) * wx;
    pw[1][2] = wz * (1.f - wx);         pw[1][3] = wz * wx;
    pw[2][0] = (1.f - wz) * (1.f - wy); pw[2][1] = (1.f - wz) * wy;
    pw[2][2] = wz * (1.f - wy);         pw[2][3] = wz * wy;
    float lw[3] = { wz, wy, wx };

    float vm[6] = { 0.f, 0.f, 0.f, 0.f, 0.f, 0.f };
#pragma unroll
    for (int p = 0; p < 3; ++p) {
        float s0 = pw[p][0], s1 = pw[p][1], s2 = pw[p][2], s3 = pw[p][3];
        float il = 1.f - lw[p], wl = lw[p];
#pragma unroll
        for (int d = 0; d < 3; ++d) {               // dword d -> ch 2d, 2d+1
            u32 a = q[4 * p + 0][d], b = q[4 * p + 1][d];
            u32 cc = q[4 * p + 2][d], dd = q[4 * p + 3][d];
            float slo = s0 * lobf(a) + s1 * lobf(b) + s2 * lobf(cc) + s3 * lobf(dd);
            float shi = s0 * hibf(a) + s1 * hibf(b) + s2 * hibf(cc) + s3 * hibf(dd);
            float llo = il * lobf(le[p][d]) + wl * lobf(lf[p][d]);
            float lhi = il * hibf(le[p][d]) + wl * hibf(lf[p][d]);
            vm[2 * d + 0] = fmaf(slo, llo, vm[2 * d + 0]);
            vm[2 * d + 1] = fmaf(shi, lhi, vm[2 * d + 1]);
        }
    }

    float* vr = vm_lds + ptL * VMS + 6 * c;
    *(float2*)(vr + 0) = make_float2(vm[0], vm[1]);
    *(float2*)(vr + 2) = make_float2(vm[2], vm[3]);
    *(float2*)(vr + 4) = make_float2(vm[4], vm[5]);

    __syncthreads();

    int wav = __builtin_amdgcn_readfirstlane(tid >> 6);   // 0..7, wave-uniform
    int lane = tid & 63;                                  // local point
    int ob = wav * 4;

    const float* vmrow = vm_lds + lane * VMS;
    float4 bb = *(const float4*)(Bb + ob);                // uniform -> s_load
    float a0 = bb.x, a1 = bb.y, a2 = bb.z, a3 = bb.w;
#pragma unroll 4
    for (int k = 0; k < 12; ++k) {
        float4 v = *(const float4*)(vmrow + 4 * k);       // ds_read_b128
        float4 w0 = *(const float4*)(W + (ob + 0) * RANK + 4 * k);  // s_loads
        float4 w1 = *(const float4*)(W + (ob + 1) * RANK + 4 * k);
        float4 w2 = *(const float4*)(W + (ob + 2) * RANK + 4 * k);
        float4 w3 = *(const float4*)(W + (ob + 3) * RANK + 4 * k);
        a0 = fmaf(v.x, w0.x, a0); a0 = fmaf(v.y, w0.y, a0);
        a0 = fmaf(v.z, w0.z, a0); a0 = fmaf(v.w, w0.w, a0);
        a1 = fmaf(v.x, w1.x, a1); a1 = fmaf(v.y, w1.y, a1);
        a1 = fmaf(v.z, w1.z, a1); a1 = fmaf(v.w, w1.w, a1);
        a2 = fmaf(v.x, w2.x, a2); a2 = fmaf(v.y, w2.y, a2);
        a2 = fmaf(v.z, w2.z, a2); a2 = fmaf(v.w, w2.w, a2);
        a3 = fmaf(v.x, w3.x, a3); a3 = fmaf(v.y, w3.y, a3);
        a3 = fmaf(v.z, w3.z, a3); a3 = fmaf(v.w, w3.w, a3);
    }

    // ---- output staging: full 128B rows per wave; rows scattered by orig id
    __syncthreads();
    {
        vf4 r; r.x = a0; r.y = a1; r.z = a2; r.w = a3;
        *(vf4*)(vm_lds + lane * OSTR + ob) = r;
    }
    __syncthreads();
    {
        int p8 = lane >> 3;
        int c2 = lane & 7;
        int gp = wav * 8 + p8;
        vf4 v = *(const vf4*)(vm_lds + gp * OSTR + 4 * c2);
        size_t orow = (size_t)opt_lds[gp];
        __builtin_nontemporal_store(v, (vf4*)(out + orow * ODIM + 4 * c2));
    }
}

// ---------- Launch ----------------------------------------------------------
template <int TEXB>
static void launch_unsorted(const float* coords, const float* pxy, const float* pxz,
                            const float* pyz, const float* lz, const float* ly,
                            const float* lx, const float* W, const float* Bb,
                            float* out, char* ws, hipStream_t stream) {
    dim3 gt(TEXELS / TT, 3);
    transpose_planes<TEXB><<<gt, 256, 0, stream>>>(pxy, pxz, pyz, ws);
    transpose_lines<TEXB><<<6, 256, 0, stream>>>(lz, ly, lx, ws);
    geo_main<TEXB, false><<<NPTS / PPB, 512, 0, stream>>>(coords, ws, W, Bb, out);
}

extern "C" void kernel_launch(void* const* d_in, const int* in_sizes, int n_in,
                              void* d_out, int out_size, void* d_ws, size_t ws_size,
                              hipStream_t stream) {
    const float* coords = (const float*)d_in[0];
    const float* pxy = (const float*)d_in[1];
    const float* pxz = (const float*)d_in[2];
    const float* pyz = (const float*)d_in[3];
    const float* lz = (const float*)d_in[4];
    const float* ly = (const float*)d_in[5];
    const float* lx = (const float*)d_in[6];
    const float* W = (const float*)d_in[7];
    const float* Bb = (const float*)d_in[8];
    float* out = (float*)d_out;
    char* ws = (char*)d_ws;

    // sorted path layout (TEXB=96)
    size_t pool96 = (size_t)3 * TEXELS * 96 + (size_t)3 * RES * 96;   // 75,644,928
    size_t o_counts = (pool96 + 255) & ~(size_t)255;
    size_t o_cursors = o_counts + (size_t)CELLS * 4;
    size_t o_rc2 = o_cursors + (size_t)CELLS * 4;
    size_t need_sorted = o_rc2 + (size_t)NPTS * 16;                   // ~91.9 MB
    size_t need128 = (size_t)3 * TEXELS * 128 + (size_t)3 * RES * 128;

    if (ws_size >= need_sorted) {
        u32* counts = (u32*)(ws + o_counts);
        u32* cursors = (u32*)(ws + o_cursors);
        vf4* rc2 = (vf4*)(ws + o_rc2);

        hipMemsetAsync(counts, 0, (size_t)CELLS * 4, stream);
        k1_count_tp<<<CNTB + TPA, 256, 0, stream>>>(coords, counts,
                                                    pxy, pxz, pyz, ws);
        k2_scan_lines_tp<<<7 + TPB, 256, 0, stream>>>(counts, cursors,
                                                      lz, ly, lx,
                                                      pxy, pxz, pyz, ws);
        k3_scatter_tp<<<CNTB + TPC, 256, 0, stream>>>(coords, cursors, rc2,
                                                      pxy, pxz, pyz, ws);
        geo_main<96, true><<<NPTS / PPB, 512, 0, stream>>>(rc2, ws, W, Bb, out);
    } else if (ws_size >= need128) {
        launch_unsorted<128>(coords, pxy, pxz, pyz, lz, ly, lx, W, Bb, out, ws, stream);
    } else {
        launch_unsorted<96>(coords, pxy, pxz, pyz, lz, ly, lx, W, Bb, out, ws, stream);
    }
}